// Round 1
// baseline (167.697 us; speedup 1.0000x reference)
//
#include <hip/hip_runtime.h>

// ---------------- problem constants ----------------
#define GRID_N   50
#define YDIM     2500      // 50*50
#define BATCH    16
#define NCTX     64
#define NTGT     128
#define BN       1024      // BATCH*NCTX
#define RDIM     128
#define ZDIM     64
#define HDIM     128
#define CCONV    32
#define NSTRIP   5         // 5 strips of 10 rows
#define STRIPROWS 10

typedef __attribute__((ext_vector_type(8))) short  s8v;   // 8 x bf16 (4 VGPR)
typedef __attribute__((ext_vector_type(4))) float  f4v;   // MFMA accum

__device__ __forceinline__ unsigned short f2bf(float f) {
    unsigned int u = __float_as_uint(f);
    u += 0x7FFFu + ((u >> 16) & 1u);
    return (unsigned short)(u >> 16);
}
__device__ __forceinline__ float bf2f(unsigned short h) {
    return __uint_as_float(((unsigned int)h) << 16);
}

// ---------------- ws layout (bytes) ----------------
// w2 pack:  9*2*64*8 bf16                = 18432
// wd pack:  2 * 157*4*64*8 bf16          = 1286144   @ 18432
// part:     1024*5*32 f32                = 655360    @ 1304576
// r_i:      1024*128 f32                 = 524288    @ 1959936
// z:        16*64 f32                    = 4096      @ 2484224
// h2d:      2048*128 bf16                = 524288    @ 2488320
// total 3012608 bytes

// =====================================================================
// pack w2 [cout][cin][3][3] f32 -> MFMA B fragments bf16
// layout: frag[(tap*2+nt)*64 + lane][8] ; B[k][n]: n = nt*16+(l&15),
// k-within-step = (l>>4)*8 + j  (k-step = tap, cin inner)
// =====================================================================
__global__ void k_pack_w2(const float* __restrict__ w2, unsigned short* __restrict__ w2p)
{
    int t = threadIdx.x;
    int l = t & 63, q = t >> 6;
    int cout_lo = l & 15, cb = (l >> 4) & 3;
    for (int e = q; e < 18; e += 4) {
        int tap = e >> 1, ntt = e & 1;
        int cout = ntt * 16 + cout_lo;
        unsigned int pk[4];
#pragma unroll
        for (int g = 0; g < 4; ++g) {
            int cin0 = cb * 8 + 2 * g;
            unsigned int lo = f2bf(w2[(cout * 32 + cin0) * 9 + tap]);
            unsigned int hi = f2bf(w2[(cout * 32 + cin0 + 1) * 9 + tap]);
            pk[g] = lo | (hi << 16);
        }
        uint4 o; o.x = pk[0]; o.y = pk[1]; o.z = pk[2]; o.w = pk[3];
        *(uint4*)&w2p[((tap * 2 + ntt) * 64 + l) * 8] = o;
    }
}

// =====================================================================
// pack Wdmu/Wdsig [128][2500] f32 -> B fragments bf16 (zero-padded tail)
// frag[((nt*4+ks)*64 + lane)][8] ; n = nt*16+(l&15), k = ks*32+(l>>4)*8+j
// =====================================================================
__global__ void k_pack_wd(const float* __restrict__ Wmu, const float* __restrict__ Wsg,
                          unsigned short* __restrict__ wdp)
{
    int nt = blockIdx.x;          // 0..156
    int which = blockIdx.y;       // 0: mu, 1: sig
    const float* W = which ? Wsg : Wmu;
    unsigned short* outp = wdp + (size_t)which * (157 * 4 * 64 * 8);
    int t = threadIdx.x;
    int l = t & 63, ks = t >> 6;
    int n = nt * 16 + (l & 15);
    int kbase = ks * 32 + ((l >> 4) & 3) * 8;
    unsigned int pk[4];
#pragma unroll
    for (int g = 0; g < 4; ++g) {
        float f0 = (n < 2500) ? W[(kbase + 2 * g) * 2500 + n] : 0.f;
        float f1 = (n < 2500) ? W[(kbase + 2 * g + 1) * 2500 + n] : 0.f;
        pk[g] = (unsigned int)f2bf(f0) | ((unsigned int)f2bf(f1) << 16);
    }
    uint4 o; o.x = pk[0]; o.y = pk[1]; o.z = pk[2]; o.w = pk[3];
    *(uint4*)&outp[((nt * 4 + ks) * 64 + l) * 8] = o;
}

// =====================================================================
// conv1 (fp32 VALU) + conv2 (bf16 MFMA implicit GEMM) + ReLU + pooled
// partial sums. One block per (sample, strip of 10 output rows).
// h1 LDS layout: [pos = br*52 + bc][cin] bf16, 16B granule XOR-swizzled:
// slot = blk ^ ((pos>>1)&3)
// =====================================================================
__global__ __launch_bounds__(256, 2) void k_conv(
    const float* __restrict__ xc, const float* __restrict__ yc,
    const float* __restrict__ w1, const float* __restrict__ b1,
    const float* __restrict__ b2, const unsigned short* __restrict__ w2p,
    float* __restrict__ part)
{
    __shared__ __align__(16) unsigned short h1[12 * 52 * 32];  // 39936 B
    __shared__ __align__(16) float ypad[14 * 52];
    __shared__ float w1y[288];
    __shared__ float Tt[288];
    __shared__ float b1s[32];
    __shared__ float redbuf[128];

    const int t = threadIdx.x;
    const int lane = t & 63, wid = t >> 6;
    const int blk = blockIdx.x;
    const int s = blk / NSTRIP, strip = blk % NSTRIP;
    const int r0 = strip * STRIPROWS;

    { // zero h1 (halos + padded-M safety)
        uint4 z4; z4.x = z4.y = z4.z = z4.w = 0u;
        uint4* p = (uint4*)h1;
        for (int i = t; i < (12 * 52 * 32 * 2) / 16; i += 256) p[i] = z4;
    }
    // w1 y-channel weights + x-channel region sums
    for (int e = t; e < 288; e += 256) {
        int c = e / 9, tap = e % 9;
        w1y[e] = w1[(c * 2 + 0) * 9 + tap];
        int rr = tap / 3, cc = tap % 3;   // region index shares the e%9 decomposition
        float sum = 0.f;
        for (int ky = 0; ky < 3; ++ky)
            for (int kx = 0; kx < 3; ++kx) {
                bool rok = !((rr == 0 && ky == 0) || (rr == 2 && ky == 2));
                bool cok = !((cc == 0 && kx == 0) || (cc == 2 && kx == 2));
                if (rok && cok) sum += w1[(c * 2 + 1) * 9 + ky * 3 + kx];
            }
        Tt[e] = sum;
    }
    if (t < 32) b1s[t] = b1[t];
    // zero-padded y strip: rows gy = r0-2 .. r0+11, halo cols
    for (int e = t; e < 14 * 52; e += 256) {
        int ry = e / 52, col = e % 52;
        int gy = r0 - 2 + ry, gc = col - 1;
        float v = 0.f;
        if (gy >= 0 && gy < GRID_N && gc >= 0 && gc < GRID_N)
            v = yc[s * YDIM + gy * GRID_N + gc];
        ypad[e] = v;
    }
    const float x = xc[s];
    __syncthreads();

    // ---------------- conv1: each wave owns 8 cin ----------------
    {
        const int cin0 = wid * 8;
        float w1r[9][8];
#pragma unroll
        for (int tap = 0; tap < 9; ++tap)
#pragma unroll
            for (int j = 0; j < 8; ++j) w1r[tap][j] = w1y[(cin0 + j) * 9 + tap];
        float b1v[8];
#pragma unroll
        for (int j = 0; j < 8; ++j) b1v[j] = b1s[cin0 + j];

        for (int it = 0; it < 10; ++it) {
            int p = lane + it * 64;               // 0..639, 12 rows x 50 cols = 600
            if (p < 600) {
                int br = p / 50, c = p % 50;
                int gr = r0 - 1 + br;
                if (gr >= 0 && gr < GRID_N) {
                    float yv[9];
#pragma unroll
                    for (int ky = 0; ky < 3; ++ky)
#pragma unroll
                        for (int kx = 0; kx < 3; ++kx)
                            yv[ky * 3 + kx] = ypad[(br + ky) * 52 + c + kx];
                    int rr = (gr == 0) ? 0 : ((gr == GRID_N - 1) ? 2 : 1);
                    int cc = (c == 0) ? 0 : ((c == GRID_N - 1) ? 2 : 1);
                    int ridx = rr * 3 + cc;
                    float acc[8];
#pragma unroll
                    for (int j = 0; j < 8; ++j)
                        acc[j] = fmaf(x, Tt[(cin0 + j) * 9 + ridx], b1v[j]);
#pragma unroll
                    for (int tap = 0; tap < 9; ++tap)
#pragma unroll
                        for (int j = 0; j < 8; ++j)
                            acc[j] = fmaf(yv[tap], w1r[tap][j], acc[j]);
                    unsigned int pk[4];
#pragma unroll
                    for (int g = 0; g < 4; ++g) {
                        unsigned int lo = f2bf(fmaxf(acc[2 * g], 0.f));
                        unsigned int hi = f2bf(fmaxf(acc[2 * g + 1], 0.f));
                        pk[g] = lo | (hi << 16);
                    }
                    int pos = br * 52 + (c + 1);
                    int slot = wid ^ ((pos >> 1) & 3);
                    uint4 v4; v4.x = pk[0]; v4.y = pk[1]; v4.z = pk[2]; v4.w = pk[3];
                    *(uint4*)&h1[pos * 32 + slot * 8] = v4;
                }
            }
        }
    }
    __syncthreads();

    // ---------------- conv2: MFMA 16x16x32, M=512(pad), N=32, K=288 ----------------
    s8v bfr[9][2];
    const s8v* wf = (const s8v*)w2p;
#pragma unroll
    for (int tp = 0; tp < 9; ++tp) {
        bfr[tp][0] = wf[(tp * 2 + 0) * 64 + lane];
        bfr[tp][1] = wf[(tp * 2 + 1) * 64 + lane];
    }
    f4v acc[8][2];
    {
        f4v zf = {0.f, 0.f, 0.f, 0.f};
#pragma unroll
        for (int mi = 0; mi < 8; ++mi) { acc[mi][0] = zf; acc[mi][1] = zf; }
    }
    const int lcol = lane & 15, lblk = lane >> 4;
#pragma unroll
    for (int mi = 0; mi < 8; ++mi) {
        int mt = mi * 4 + wid;
        int m = mt * 16 + lcol;
        int mr = m / 50, mc = m % 50;
        int pc = (m < 500) ? (mr * 52 + mc) : 0;   // clamp padded rows (discarded)
#pragma unroll
        for (int tp = 0; tp < 9; ++tp) {
            int ky = tp / 3, kx = tp % 3;
            int pos = pc + ky * 52 + kx;
            int slot = lblk ^ ((pos >> 1) & 3);
            s8v a = *(const s8v*)&h1[pos * 32 + slot * 8];
            acc[mi][0] = __builtin_amdgcn_mfma_f32_16x16x32_bf16(a, bfr[tp][0], acc[mi][0], 0, 0, 0);
            acc[mi][1] = __builtin_amdgcn_mfma_f32_16x16x32_bf16(a, bfr[tp][1], acc[mi][1], 0, 0, 0);
        }
    }

    // ---------------- fused bias + ReLU + spatial partial sum ----------------
    float b2v0 = b2[lcol], b2v1 = b2[16 + lcol];
    float ps0 = 0.f, ps1 = 0.f;
#pragma unroll
    for (int mi = 0; mi < 8; ++mi) {
        int mt = mi * 4 + wid;
        int mb = mt * 16 + lblk * 4;
#pragma unroll
        for (int r = 0; r < 4; ++r) {
            if (mb + r < 500) {
                ps0 += fmaxf(acc[mi][0][r] + b2v0, 0.f);
                ps1 += fmaxf(acc[mi][1][r] + b2v1, 0.f);
            }
        }
    }
    ps0 += __shfl_xor(ps0, 16); ps0 += __shfl_xor(ps0, 32);
    ps1 += __shfl_xor(ps1, 16); ps1 += __shfl_xor(ps1, 32);
    if (lane < 16) {
        redbuf[wid * 32 + lane] = ps0;
        redbuf[wid * 32 + 16 + lane] = ps1;
    }
    __syncthreads();
    if (t < 32) {
        float v = redbuf[t] + redbuf[32 + t] + redbuf[64 + t] + redbuf[96 + t];
        part[(s * NSTRIP + strip) * 32 + t] = v;
    }
}

// =====================================================================
// per-sample encoder MLP: pooled -> relu(feat@We1) -> r_i
// =====================================================================
__global__ void k_enc(const float* __restrict__ part, const float* __restrict__ xc,
                      const float* __restrict__ We1, const float* __restrict__ be1,
                      const float* __restrict__ We2, const float* __restrict__ be2,
                      float* __restrict__ r_i)
{
    __shared__ float feat[33];
    __shared__ float h[128];
    int s = blockIdx.x, j = threadIdx.x;
    if (j < 32) {
        float v = 0.f;
#pragma unroll
        for (int st = 0; st < NSTRIP; ++st) v += part[(s * NSTRIP + st) * 32 + j];
        feat[j] = v * (1.f / 2500.f);
    }
    if (j == 0) feat[32] = xc[s];
    __syncthreads();
    float a = be1[j];
    for (int k = 0; k < 33; ++k) a = fmaf(feat[k], We1[k * 128 + j], a);
    h[j] = fmaxf(a, 0.f);
    __syncthreads();
    float r = be2[j];
    for (int k = 0; k < 128; ++k) r = fmaf(h[k], We2[k * 128 + j], r);
    r_i[s * 128 + j] = r;
}

// =====================================================================
// aggregate r over context, mu/sigma encoder, z = mu + sigma*eps
// =====================================================================
__global__ void k_ms(const float* __restrict__ r_i,
                     const float* __restrict__ Wh, const float* __restrict__ bh,
                     const float* __restrict__ Wmu, const float* __restrict__ bmu,
                     const float* __restrict__ Wsig, const float* __restrict__ bsig,
                     const float* __restrict__ eps, float* __restrict__ out,
                     float* __restrict__ zbuf)
{
    __shared__ float r[128], hr[128];
    int b = blockIdx.x, j = threadIdx.x;
    float acc = 0.f;
    for (int i = 0; i < NCTX; ++i) acc += r_i[(b * NCTX + i) * 128 + j];
    r[j] = acc * (1.f / 64.f);
    __syncthreads();
    float a = bh[j];
    for (int k = 0; k < 128; ++k) a = fmaf(r[k], Wh[k * 128 + j], a);
    hr[j] = fmaxf(a, 0.f);
    __syncthreads();
    if (j < 64) {
        float m = bmu[j], sg = bsig[j];
        for (int k = 0; k < 128; ++k) {
            m  = fmaf(hr[k], Wmu[k * 64 + j], m);
            sg = fmaf(hr[k], Wsig[k * 64 + j], sg);
        }
        float sig = 0.1f + 0.9f / (1.f + expf(-sg));
        out[10240000 + b * 64 + j] = m;      // mu_c
        out[10241024 + b * 64 + j] = sig;    // sigma_c
        zbuf[b * 64 + j] = m + sig * eps[b * 64 + j];
    }
}

// =====================================================================
// decoder hidden: h2 = relu(relu(xz@Wd1+bd1)@Wd2+bd2), bf16 out.
// xz rows of one batch differ only in the x scalar -> z-dot hoisted.
// 8 rows per block (all same batch), 4-row register batching.
// =====================================================================
__global__ void k_dec1(const float* __restrict__ xt, const float* __restrict__ zbuf,
                       const float* __restrict__ Wd1, const float* __restrict__ bd1,
                       const float* __restrict__ Wd2, const float* __restrict__ bd2,
                       unsigned short* __restrict__ h2d)
{
    __shared__ float zsh[64];
    __shared__ float h1sh[4][128];
    int j = threadIdx.x;
    int r0 = blockIdx.x * 8;
    int b = r0 >> 7;
    if (j < 64) zsh[j] = zbuf[b * 64 + j];
    __syncthreads();
    float v = bd1[j];
    for (int k = 0; k < 64; ++k) v = fmaf(zsh[k], Wd1[(1 + k) * 128 + j], v);
    float w0 = Wd1[j];
    float bd2j = bd2[j];
    for (int u0 = 0; u0 < 8; u0 += 4) {
#pragma unroll
        for (int u = 0; u < 4; ++u) {
            float xv = xt[r0 + u0 + u];
            h1sh[u][j] = fmaxf(fmaf(xv, w0, v), 0.f);
        }
        __syncthreads();
        float a[4];
#pragma unroll
        for (int u = 0; u < 4; ++u) a[u] = bd2j;
        for (int k = 0; k < 128; ++k) {
            float wv = Wd2[k * 128 + j];
#pragma unroll
            for (int u = 0; u < 4; ++u) a[u] = fmaf(h1sh[u][k], wv, a[u]);
        }
#pragma unroll
        for (int u = 0; u < 4; ++u)
            h2d[(size_t)(r0 + u0 + u) * 128 + j] = f2bf(fmaxf(a[u], 0.f));
        __syncthreads();
    }
}

// =====================================================================
// big decoder GEMM: [2048,128] @ [128,2500] (x2: mu & sigma heads),
// fused bias (+softplus for sigma). A in swizzled LDS, B pre-packed.
// =====================================================================
__global__ __launch_bounds__(256) void k_gemm(
    const unsigned short* __restrict__ h2d, const unsigned short* __restrict__ wdp,
    const float* __restrict__ bdmu, const float* __restrict__ bdsg,
    float* __restrict__ out)
{
    __shared__ __align__(16) unsigned short Al[64 * 128];
    int t = threadIdx.x, lane = t & 63, w = t >> 6;
    int m0 = blockIdx.x * 64;
    int which = blockIdx.z;
    // stage A (64 rows x 128 k bf16), XOR swizzle: blk ^= (row&7)
#pragma unroll
    for (int i = 0; i < 4; ++i) {
        int g = t + i * 256;
        int row = g >> 4, bk = g & 15;
        uint4 v = *(const uint4*)&h2d[(size_t)(m0 + row) * 128 + bk * 8];
        *(uint4*)&Al[row * 128 + ((bk ^ (row & 7)) << 3)] = v;
    }
    __syncthreads();
    int nt = blockIdx.y * 4 + w;
    if (nt < 157) {
        const unsigned short* wp = wdp + (size_t)which * (157 * 4 * 64 * 8);
        s8v bfr[4];
#pragma unroll
        for (int ks = 0; ks < 4; ++ks)
            bfr[ks] = *(const s8v*)&wp[((nt * 4 + ks) * 64 + lane) * 8];
        f4v acc[4];
        {
            f4v zf = {0.f, 0.f, 0.f, 0.f};
#pragma unroll
            for (int mt = 0; mt < 4; ++mt) acc[mt] = zf;
        }
        int lcol = lane & 15, lq = lane >> 4;
#pragma unroll
        for (int mt = 0; mt < 4; ++mt) {
            int mrow = mt * 16 + lcol;
#pragma unroll
            for (int ks = 0; ks < 4; ++ks) {
                int bk = ks * 4 + lq;
                s8v a = *(const s8v*)&Al[mrow * 128 + ((bk ^ (mrow & 7)) << 3)];
                acc[mt] = __builtin_amdgcn_mfma_f32_16x16x32_bf16(a, bfr[ks], acc[mt], 0, 0, 0);
            }
        }
        int col = nt * 16 + lcol;
        if (col < 2500) {
            const float* bp = which ? bdsg : bdmu;
            float bv = bp[col];
            size_t zoff = (size_t)which * 5120000;
#pragma unroll
            for (int mt = 0; mt < 4; ++mt)
#pragma unroll
                for (int r = 0; r < 4; ++r) {
                    int row = m0 + mt * 16 + lq * 4 + r;
                    float vv = acc[mt][r] + bv;
                    if (which) {
                        float sp = fmaxf(vv, 0.f) + log1pf(expf(-fabsf(vv)));
                        vv = 0.1f + 0.9f * sp;
                    }
                    out[zoff + (size_t)row * 2500 + col] = vv;
                }
        }
    }
}

// =====================================================================
extern "C" void kernel_launch(void* const* d_in, const int* in_sizes, int n_in,
                              void* d_out, int out_size, void* d_ws, size_t ws_size,
                              hipStream_t stream)
{
    const float* xc   = (const float*)d_in[0];
    const float* yc   = (const float*)d_in[1];
    const float* xt   = (const float*)d_in[2];
    const float* eps  = (const float*)d_in[3];
    const float* w1   = (const float*)d_in[4];
    const float* b1   = (const float*)d_in[5];
    const float* w2   = (const float*)d_in[6];
    const float* b2   = (const float*)d_in[7];
    const float* We1  = (const float*)d_in[8];
    const float* be1  = (const float*)d_in[9];
    const float* We2  = (const float*)d_in[10];
    const float* be2  = (const float*)d_in[11];
    const float* Wh   = (const float*)d_in[12];
    const float* bh   = (const float*)d_in[13];
    const float* Wmu  = (const float*)d_in[14];
    const float* bmu  = (const float*)d_in[15];
    const float* Wsig = (const float*)d_in[16];
    const float* bsig = (const float*)d_in[17];
    const float* Wd1  = (const float*)d_in[18];
    const float* bd1  = (const float*)d_in[19];
    const float* Wd2  = (const float*)d_in[20];
    const float* bd2  = (const float*)d_in[21];
    const float* Wdmu = (const float*)d_in[22];
    const float* bdmu = (const float*)d_in[23];
    const float* Wdsg = (const float*)d_in[24];
    const float* bdsg = (const float*)d_in[25];

    float* out = (float*)d_out;
    char* wsb  = (char*)d_ws;
    unsigned short* w2p = (unsigned short*)(wsb + 0);
    unsigned short* wdp = (unsigned short*)(wsb + 18432);
    float* part = (float*)(wsb + 1304576);
    float* r_i  = (float*)(wsb + 1959936);
    float* zbuf = (float*)(wsb + 2484224);
    unsigned short* h2d = (unsigned short*)(wsb + 2488320);

    hipLaunchKernelGGL(k_pack_w2, dim3(1), dim3(256), 0, stream, w2, w2p);
    hipLaunchKernelGGL(k_pack_wd, dim3(157, 2), dim3(256), 0, stream, Wdmu, Wdsg, wdp);
    hipLaunchKernelGGL(k_conv, dim3(BN * NSTRIP), dim3(256), 0, stream,
                       xc, yc, w1, b1, b2, w2p, part);
    hipLaunchKernelGGL(k_enc, dim3(BN), dim3(128), 0, stream,
                       part, xc, We1, be1, We2, be2, r_i);
    hipLaunchKernelGGL(k_ms, dim3(BATCH), dim3(128), 0, stream,
                       r_i, Wh, bh, Wmu, bmu, Wsig, bsig, eps, out, zbuf);
    hipLaunchKernelGGL(k_dec1, dim3(256), dim3(128), 0, stream,
                       xt, zbuf, Wd1, bd1, Wd2, bd2, h2d);
    hipLaunchKernelGGL(k_gemm, dim3(32, 40, 2), dim3(256), 0, stream,
                       h2d, wdp, bdmu, bdsg, out);
}

// Round 2
// 150.443 us; speedup vs baseline: 1.1147x; 1.1147x over previous
//
#include <hip/hip_runtime.h>

// ---------------- problem constants ----------------
#define GRID_N   50
#define YDIM     2500      // 50*50
#define BATCH    16
#define NCTX     64
#define NTGT     128
#define BN       1024      // BATCH*NCTX
#define RDIM     128
#define ZDIM     64
#define HDIM     128
#define CCONV    32
#define NSTRIP   5         // 5 strips of 10 rows
#define STRIPROWS 10

typedef __attribute__((ext_vector_type(8))) short  s8v;   // 8 x bf16 (4 VGPR)
typedef __attribute__((ext_vector_type(4))) float  f4v;   // MFMA accum
typedef __attribute__((ext_vector_type(4))) unsigned int u4v;

__device__ __forceinline__ unsigned short f2bf(float f) {
    unsigned int u = __float_as_uint(f);
    u += 0x7FFFu + ((u >> 16) & 1u);
    return (unsigned short)(u >> 16);
}
__device__ __forceinline__ unsigned int cvtpk(float lo, float hi) {
    unsigned int r;
    asm("v_cvt_pk_bf16_f32 %0, %1, %2" : "=v"(r) : "v"(lo), "v"(hi));
    return r;
}

// ---------------- ws layout (bytes) ----------------
// w2p: 18432 @0 ; wdp: 1286144 @18432 ; part: 655360 @1304576 ;
// r_i: 524288 @1959936 ; zbuf: 4096 @2484224 ; h2d: 524288 @2488320 ;
// w1p: 2048 @3012608  -> total 3014656

// ---------------- k_conv smem layout ----------------
#define PLB   49920        // planes base byte (h1 = 624 pos * 80B)
#define PY    2            // y-plane elem base (within planes)
#define PX    738          // x-plane
#define P1    1490         // ones-plane
#define DUP   2228         // +1-shifted duplicate: pl[DUP+k] = pl[k+3]
#define OFFT  58824        // offtab (16 ints)
#define REDB  58888        // redbuf (128 floats)
#define SMEMB 59408

// =====================================================================
// pack w2 -> MFMA B frags (16x16x32) and w1(+b1) -> conv1 A frags (C^T)
// w2p: frag[(tap*2+nt)*64 + l][8]: n = nt*16+(l&15), k-in-step=(l>>4)*8+j
// w1p: frag[(ct*64+l)*8+j] = W1mat[(l>>4)*8+j][ct*16+(l&15)]
// =====================================================================
__global__ void k_pack_w(const float* __restrict__ w1, const float* __restrict__ b1,
                         const float* __restrict__ w2,
                         unsigned short* __restrict__ w2p, unsigned short* __restrict__ w1p)
{
    int t = threadIdx.x;
    int l = t & 63, qq = t >> 6;
    int cout_lo = l & 15, cb = (l >> 4) & 3;
    for (int e = qq; e < 18; e += 4) {
        int tap = e >> 1, ntt = e & 1;
        int cout = ntt * 16 + cout_lo;
        unsigned int pk[4];
#pragma unroll
        for (int g = 0; g < 4; ++g) {
            int cin0 = cb * 8 + 2 * g;
            unsigned int lo = f2bf(w2[(cout * 32 + cin0) * 9 + tap]);
            unsigned int hi = f2bf(w2[(cout * 32 + cin0 + 1) * 9 + tap]);
            pk[g] = lo | (hi << 16);
        }
        uint4 o; o.x = pk[0]; o.y = pk[1]; o.z = pk[2]; o.w = pk[3];
        *(uint4*)&w2p[((tap * 2 + ntt) * 64 + l) * 8] = o;
    }
    if (t < 128) {
        int ct = t >> 6, lane = t & 63;
        int c = ct * 16 + (lane & 15), q2 = lane >> 4;
        // k-slot map: 0..8 = y tap, 16+t = x tap, 32 = bias(ones), -1 = zero
        const signed char kmap[32] = {0,1,3,4,6,7,16,17,  2,-1,5,-1,8,-1,18,-1,
                                      19,20,21,-1,22,23,24,-1, 32,-1,-1,-1,-1,-1,-1,-1};
        unsigned short v8[8];
#pragma unroll
        for (int j = 0; j < 8; ++j) {
            int km = kmap[q2 * 8 + j];
            float v = 0.f;
            if (km == 32) v = b1[c];
            else if (km >= 16) v = w1[(c * 2 + 1) * 9 + (km - 16)];
            else if (km >= 0) v = w1[(c * 2 + 0) * 9 + km];
            v8[j] = f2bf(v);
        }
        uint4 o;
        o.x = (unsigned)v8[0] | ((unsigned)v8[1] << 16);
        o.y = (unsigned)v8[2] | ((unsigned)v8[3] << 16);
        o.z = (unsigned)v8[4] | ((unsigned)v8[5] << 16);
        o.w = (unsigned)v8[6] | ((unsigned)v8[7] << 16);
        *(uint4*)&w1p[(ct * 64 + lane) * 8] = o;
    }
}

// =====================================================================
// pack Wdmu/Wdsig [128][2500] f32 -> B fragments bf16 (zero-padded tail)
// =====================================================================
__global__ void k_pack_wd(const float* __restrict__ Wmu, const float* __restrict__ Wsg,
                          unsigned short* __restrict__ wdp)
{
    int nt = blockIdx.x;          // 0..156
    int which = blockIdx.y;       // 0: mu, 1: sig
    const float* W = which ? Wsg : Wmu;
    unsigned short* outp = wdp + (size_t)which * (157 * 4 * 64 * 8);
    int t = threadIdx.x;
    int l = t & 63, ks = t >> 6;
    int n = nt * 16 + (l & 15);
    int kbase = ks * 32 + ((l >> 4) & 3) * 8;
    unsigned int pk[4];
#pragma unroll
    for (int g = 0; g < 4; ++g) {
        float f0 = (n < 2500) ? W[(kbase + 2 * g) * 2500 + n] : 0.f;
        float f1 = (n < 2500) ? W[(kbase + 2 * g + 1) * 2500 + n] : 0.f;
        pk[g] = (unsigned int)f2bf(f0) | ((unsigned int)f2bf(f1) << 16);
    }
    uint4 o; o.x = pk[0]; o.y = pk[1]; o.z = pk[2]; o.w = pk[3];
    *(uint4*)&outp[((nt * 4 + ks) * 64 + l) * 8] = o;
}

// =====================================================================
// conv1 + conv2 both as bf16 MFMA implicit GEMM, fused relu+pool.
// One block per (sample, strip of 10 output rows).
//  - planes: y/x/ones bf16 (52-wide geometry) + shifted dup for alignment
//  - conv1: C^T = mfma(w1^T frags, plane-gather frags); write h1 [pos][cin]
//    bf16, row stride 80B (bank step 20 -> conflict-free, imm offsets)
//  - conv2: 16x16x32, M=512(pad), N=32, K=9taps*32cin; A via ds_read_b128
//    at compile-time immediate tap offsets. Fused bias+relu+spatial sum.
// =====================================================================
__global__ __launch_bounds__(256, 2) void k_conv(
    const float* __restrict__ xc, const float* __restrict__ yc,
    const unsigned short* __restrict__ w1p, const unsigned short* __restrict__ w2p,
    const float* __restrict__ b2, float* __restrict__ part)
{
    __shared__ __align__(16) char smem[SMEMB];
    unsigned short* pl = (unsigned short*)(smem + PLB);
    int* offtab = (int*)(smem + OFFT);
    float* redbuf = (float*)(smem + REDB);

    const int t = threadIdx.x, lane = t & 63, w = t >> 6;
    const int l15 = lane & 15, q = lane >> 4;
    const int blk = blockIdx.x, s = blk / NSTRIP, strip = blk - s * NSTRIP;
    const int r0 = strip * STRIPROWS;

    // weight fragments (L2-resident)
    s8v w1f[2], w2f[9][2];
#pragma unroll
    for (int ct = 0; ct < 2; ++ct)
        w1f[ct] = *(const s8v*)&w1p[(ct * 64 + lane) * 8];
#pragma unroll
    for (int tp = 0; tp < 9; ++tp) {
        w2f[tp][0] = *(const s8v*)&w2p[((tp * 2 + 0) * 64 + lane) * 8];
        w2f[tp][1] = *(const s8v*)&w2p[((tp * 2 + 1) * 64 + lane) * 8];
    }
    const float xv = xc[s];
    const unsigned short xbf = f2bf(xv);
    const float b2v0 = b2[l15], b2v1 = b2[16 + l15];

    if (t < 16) {
        const int btab[16] = {1, 53, 105, 737,   3, 55, 107, 739,
                              789, 791, 841, 843,  P1, P1, P1, P1};
        offtab[t] = btab[t];
    }
    // fill planes (+ shifted dup). ry = e/52 via magic (valid e<736)
    for (int e = t; e < 736; e += 256) {
        unsigned ry = ((unsigned)(e * 1261)) >> 16;
        int ycol = e - (int)ry * 52;
        int gy = r0 - 2 + (int)ry, gc = ycol - 1;
        bool inb = ((unsigned)gy < 50u) && ((unsigned)gc < 50u);
        unsigned short yb = 0, xb = 0;
        if (inb) { yb = f2bf(yc[s * YDIM + gy * 50 + gc]); xb = xbf; }
        int s0 = PY + e, s1 = PX + e, s2 = P1 + e;
        pl[s0] = yb; if (s0 >= 3) pl[DUP + s0 - 3] = yb;
        pl[s1] = xb; pl[DUP + s1 - 3] = xb;
        pl[s2] = 0x3F80; pl[DUP + s2 - 3] = 0x3F80;
    }
    __syncthreads();

    // ---------------- conv1: M=624 (12x52 pos space), N=32, K=32 ----------------
    int boff[4];
#pragma unroll
    for (int i = 0; i < 4; ++i) {
        int B = offtab[q * 4 + i];
        int par = (B + lane) & 1;                       // m parity == lane&1
        boff[i] = PLB + ((par ? (DUP - 3 + B) : B) << 1);
    }
    const f4v zf = {0.f, 0.f, 0.f, 0.f};
    for (int mt = w; mt < 39; mt += 4) {
        int m = mt * 16 + l15;
        int mb = m * 2;
        unsigned g0 = *(const unsigned*)(smem + boff[0] + mb);
        unsigned g1 = *(const unsigned*)(smem + boff[1] + mb);
        unsigned g2 = *(const unsigned*)(smem + boff[2] + mb);
        unsigned g3 = *(const unsigned*)(smem + boff[3] + mb);
        u4v gg = {g0, g1, g2, g3};
        s8v af = __builtin_bit_cast(s8v, gg);
        f4v c0 = __builtin_amdgcn_mfma_f32_16x16x32_bf16(w1f[0], af, zf, 0, 0, 0);
        f4v c1 = __builtin_amdgcn_mfma_f32_16x16x32_bf16(w1f[1], af, zf, 0, 0, 0);
        unsigned mr = ((unsigned)(m * 1261)) >> 16;     // m/52
        int mc = m - (int)mr * 52;
        int gy = r0 - 1 + (int)mr;
        bool valid = ((unsigned)(mc - 1) < 50u) && ((unsigned)gy < 50u);
        unsigned p0 = cvtpk(fmaxf(c0[0], 0.f), fmaxf(c0[1], 0.f));
        unsigned p1 = cvtpk(fmaxf(c0[2], 0.f), fmaxf(c0[3], 0.f));
        unsigned p2 = cvtpk(fmaxf(c1[0], 0.f), fmaxf(c1[1], 0.f));
        unsigned p3 = cvtpk(fmaxf(c1[2], 0.f), fmaxf(c1[3], 0.f));
        if (!valid) { p0 = 0u; p1 = 0u; p2 = 0u; p3 = 0u; }
        char* wp = smem + m * 80 + q * 8;               // cin = ct*16 + q*4 + j
        *(uint2*)(wp)      = make_uint2(p0, p1);
        *(uint2*)(wp + 32) = make_uint2(p2, p3);
    }
    __syncthreads();

    // ---------------- conv2: M=512(pad), N=32, K=288 ----------------
    f4v acc[8][2];
#pragma unroll
    for (int i = 0; i < 8; ++i) { acc[i][0] = zf; acc[i][1] = zf; }
#pragma unroll
    for (int tt = 0; tt < 8; ++tt) {
        int m2 = (w * 8 + tt) * 16 + l15;
        unsigned orr = ((unsigned)(m2 * 1311)) >> 16;   // m2/50
        const char* ab = smem + (m2 + (int)orr * 2) * 80 + q * 16;
#pragma unroll
        for (int ky = 0; ky < 3; ++ky)
#pragma unroll
            for (int kx = 0; kx < 3; ++kx) {
                s8v a = *(const s8v*)(ab + (ky * 52 + kx) * 80);
                acc[tt][0] = __builtin_amdgcn_mfma_f32_16x16x32_bf16(a, w2f[ky * 3 + kx][0], acc[tt][0], 0, 0, 0);
                acc[tt][1] = __builtin_amdgcn_mfma_f32_16x16x32_bf16(a, w2f[ky * 3 + kx][1], acc[tt][1], 0, 0, 0);
            }
    }
    // fused bias + relu + spatial partial sum
    float ps0 = 0.f, ps1 = 0.f;
#pragma unroll
    for (int tt = 0; tt < 8; ++tt) {
        int mbase = (w * 8 + tt) * 16 + q * 4;
#pragma unroll
        for (int r = 0; r < 4; ++r) {
            if (mbase + r < 500) {
                ps0 += fmaxf(acc[tt][0][r] + b2v0, 0.f);
                ps1 += fmaxf(acc[tt][1][r] + b2v1, 0.f);
            }
        }
    }
    ps0 += __shfl_xor(ps0, 16); ps0 += __shfl_xor(ps0, 32);
    ps1 += __shfl_xor(ps1, 16); ps1 += __shfl_xor(ps1, 32);
    if (lane < 16) {
        redbuf[w * 32 + l15] = ps0;
        redbuf[w * 32 + 16 + l15] = ps1;
    }
    __syncthreads();
    if (t < 32)
        part[(s * NSTRIP + strip) * 32 + t] =
            redbuf[t] + redbuf[32 + t] + redbuf[64 + t] + redbuf[96 + t];
}

// =====================================================================
// per-sample encoder MLP: pooled -> relu(feat@We1) -> r_i
// =====================================================================
__global__ void k_enc(const float* __restrict__ part, const float* __restrict__ xc,
                      const float* __restrict__ We1, const float* __restrict__ be1,
                      const float* __restrict__ We2, const float* __restrict__ be2,
                      float* __restrict__ r_i)
{
    __shared__ float feat[33];
    __shared__ float h[128];
    int s = blockIdx.x, j = threadIdx.x;
    if (j < 32) {
        float v = 0.f;
#pragma unroll
        for (int st = 0; st < NSTRIP; ++st) v += part[(s * NSTRIP + st) * 32 + j];
        feat[j] = v * (1.f / 2500.f);
    }
    if (j == 0) feat[32] = xc[s];
    __syncthreads();
    float a = be1[j];
    for (int k = 0; k < 33; ++k) a = fmaf(feat[k], We1[k * 128 + j], a);
    h[j] = fmaxf(a, 0.f);
    __syncthreads();
    float r = be2[j];
    for (int k = 0; k < 128; ++k) r = fmaf(h[k], We2[k * 128 + j], r);
    r_i[s * 128 + j] = r;
}

// =====================================================================
// aggregate r over context, mu/sigma encoder, z = mu + sigma*eps
// =====================================================================
__global__ void k_ms(const float* __restrict__ r_i,
                     const float* __restrict__ Wh, const float* __restrict__ bh,
                     const float* __restrict__ Wmu, const float* __restrict__ bmu,
                     const float* __restrict__ Wsig, const float* __restrict__ bsig,
                     const float* __restrict__ eps, float* __restrict__ out,
                     float* __restrict__ zbuf)
{
    __shared__ float r[128], hr[128];
    int b = blockIdx.x, j = threadIdx.x;
    float acc = 0.f;
    for (int i = 0; i < NCTX; ++i) acc += r_i[(b * NCTX + i) * 128 + j];
    r[j] = acc * (1.f / 64.f);
    __syncthreads();
    float a = bh[j];
    for (int k = 0; k < 128; ++k) a = fmaf(r[k], Wh[k * 128 + j], a);
    hr[j] = fmaxf(a, 0.f);
    __syncthreads();
    if (j < 64) {
        float m = bmu[j], sg = bsig[j];
        for (int k = 0; k < 128; ++k) {
            m  = fmaf(hr[k], Wmu[k * 64 + j], m);
            sg = fmaf(hr[k], Wsig[k * 64 + j], sg);
        }
        float sig = 0.1f + 0.9f / (1.f + expf(-sg));
        out[10240000 + b * 64 + j] = m;      // mu_c
        out[10241024 + b * 64 + j] = sig;    // sigma_c
        zbuf[b * 64 + j] = m + sig * eps[b * 64 + j];
    }
}

// =====================================================================
// decoder hidden: h2 = relu(relu(xz@Wd1+bd1)@Wd2+bd2), bf16 out.
// =====================================================================
__global__ void k_dec1(const float* __restrict__ xt, const float* __restrict__ zbuf,
                       const float* __restrict__ Wd1, const float* __restrict__ bd1,
                       const float* __restrict__ Wd2, const float* __restrict__ bd2,
                       unsigned short* __restrict__ h2d)
{
    __shared__ float zsh[64];
    __shared__ float h1sh[4][128];
    int j = threadIdx.x;
    int r0 = blockIdx.x * 8;
    int b = r0 >> 7;
    if (j < 64) zsh[j] = zbuf[b * 64 + j];
    __syncthreads();
    float v = bd1[j];
    for (int k = 0; k < 64; ++k) v = fmaf(zsh[k], Wd1[(1 + k) * 128 + j], v);
    float w0 = Wd1[j];
    float bd2j = bd2[j];
    for (int u0 = 0; u0 < 8; u0 += 4) {
#pragma unroll
        for (int u = 0; u < 4; ++u) {
            float xv = xt[r0 + u0 + u];
            h1sh[u][j] = fmaxf(fmaf(xv, w0, v), 0.f);
        }
        __syncthreads();
        float a[4];
#pragma unroll
        for (int u = 0; u < 4; ++u) a[u] = bd2j;
        for (int k = 0; k < 128; ++k) {
            float wv = Wd2[k * 128 + j];
#pragma unroll
            for (int u = 0; u < 4; ++u) a[u] = fmaf(h1sh[u][k], wv, a[u]);
        }
#pragma unroll
        for (int u = 0; u < 4; ++u)
            h2d[(size_t)(r0 + u0 + u) * 128 + j] = f2bf(fmaxf(a[u], 0.f));
        __syncthreads();
    }
}

// =====================================================================
// big decoder GEMM: [2048,128] @ [128,2500] (x2 heads), fused epilogue
// =====================================================================
__global__ __launch_bounds__(256) void k_gemm(
    const unsigned short* __restrict__ h2d, const unsigned short* __restrict__ wdp,
    const float* __restrict__ bdmu, const float* __restrict__ bdsg,
    float* __restrict__ out)
{
    __shared__ __align__(16) unsigned short Al[64 * 128];
    int t = threadIdx.x, lane = t & 63, w = t >> 6;
    int m0 = blockIdx.x * 64;
    int which = blockIdx.z;
#pragma unroll
    for (int i = 0; i < 4; ++i) {
        int g = t + i * 256;
        int row = g >> 4, bk = g & 15;
        uint4 v = *(const uint4*)&h2d[(size_t)(m0 + row) * 128 + bk * 8];
        *(uint4*)&Al[row * 128 + ((bk ^ (row & 7)) << 3)] = v;
    }
    __syncthreads();
    int nt = blockIdx.y * 4 + w;
    if (nt < 157) {
        const unsigned short* wp = wdp + (size_t)which * (157 * 4 * 64 * 8);
        s8v bfr[4];
#pragma unroll
        for (int ks = 0; ks < 4; ++ks)
            bfr[ks] = *(const s8v*)&wp[((nt * 4 + ks) * 64 + lane) * 8];
        f4v acc[4];
        {
            f4v zf = {0.f, 0.f, 0.f, 0.f};
#pragma unroll
            for (int mt = 0; mt < 4; ++mt) acc[mt] = zf;
        }
        int lcol = lane & 15, lq = lane >> 4;
#pragma unroll
        for (int mt = 0; mt < 4; ++mt) {
            int mrow = mt * 16 + lcol;
#pragma unroll
            for (int ks = 0; ks < 4; ++ks) {
                int bk = ks * 4 + lq;
                s8v a = *(const s8v*)&Al[mrow * 128 + ((bk ^ (mrow & 7)) << 3)];
                acc[mt] = __builtin_amdgcn_mfma_f32_16x16x32_bf16(a, bfr[ks], acc[mt], 0, 0, 0);
            }
        }
        int col = nt * 16 + lcol;
        if (col < 2500) {
            const float* bp = which ? bdsg : bdmu;
            float bv = bp[col];
            size_t zoff = (size_t)which * 5120000;
#pragma unroll
            for (int mt = 0; mt < 4; ++mt)
#pragma unroll
                for (int r = 0; r < 4; ++r) {
                    int row = m0 + mt * 16 + lq * 4 + r;
                    float vv = acc[mt][r] + bv;
                    if (which) {
                        float sp = fmaxf(vv, 0.f) + log1pf(expf(-fabsf(vv)));
                        vv = 0.1f + 0.9f * sp;
                    }
                    out[zoff + (size_t)row * 2500 + col] = vv;
                }
        }
    }
}

// =====================================================================
extern "C" void kernel_launch(void* const* d_in, const int* in_sizes, int n_in,
                              void* d_out, int out_size, void* d_ws, size_t ws_size,
                              hipStream_t stream)
{
    const float* xc   = (const float*)d_in[0];
    const float* yc   = (const float*)d_in[1];
    const float* xt   = (const float*)d_in[2];
    const float* eps  = (const float*)d_in[3];
    const float* w1   = (const float*)d_in[4];
    const float* b1   = (const float*)d_in[5];
    const float* w2   = (const float*)d_in[6];
    const float* b2   = (const float*)d_in[7];
    const float* We1  = (const float*)d_in[8];
    const float* be1  = (const float*)d_in[9];
    const float* We2  = (const float*)d_in[10];
    const float* be2  = (const float*)d_in[11];
    const float* Wh   = (const float*)d_in[12];
    const float* bh   = (const float*)d_in[13];
    const float* Wmu  = (const float*)d_in[14];
    const float* bmu  = (const float*)d_in[15];
    const float* Wsig = (const float*)d_in[16];
    const float* bsig = (const float*)d_in[17];
    const float* Wd1  = (const float*)d_in[18];
    const float* bd1  = (const float*)d_in[19];
    const float* Wd2  = (const float*)d_in[20];
    const float* bd2  = (const float*)d_in[21];
    const float* Wdmu = (const float*)d_in[22];
    const float* bdmu = (const float*)d_in[23];
    const float* Wdsg = (const float*)d_in[24];
    const float* bdsg = (const float*)d_in[25];

    float* out = (float*)d_out;
    char* wsb  = (char*)d_ws;
    unsigned short* w2p = (unsigned short*)(wsb + 0);
    unsigned short* wdp = (unsigned short*)(wsb + 18432);
    float* part = (float*)(wsb + 1304576);
    float* r_i  = (float*)(wsb + 1959936);
    float* zbuf = (float*)(wsb + 2484224);
    unsigned short* h2d = (unsigned short*)(wsb + 2488320);
    unsigned short* w1p = (unsigned short*)(wsb + 3012608);

    hipLaunchKernelGGL(k_pack_w, dim3(1), dim3(256), 0, stream, w1, b1, w2, w2p, w1p);
    hipLaunchKernelGGL(k_pack_wd, dim3(157, 2), dim3(256), 0, stream, Wdmu, Wdsg, wdp);
    hipLaunchKernelGGL(k_conv, dim3(BN * NSTRIP), dim3(256), 0, stream,
                       xc, yc, w1p, w2p, b2, part);
    hipLaunchKernelGGL(k_enc, dim3(BN), dim3(128), 0, stream,
                       part, xc, We1, be1, We2, be2, r_i);
    hipLaunchKernelGGL(k_ms, dim3(BATCH), dim3(128), 0, stream,
                       r_i, Wh, bh, Wmu, bmu, Wsig, bsig, eps, out, zbuf);
    hipLaunchKernelGGL(k_dec1, dim3(256), dim3(128), 0, stream,
                       xt, zbuf, Wd1, bd1, Wd2, bd2, h2d);
    hipLaunchKernelGGL(k_gemm, dim3(32, 40, 2), dim3(256), 0, stream,
                       h2d, wdp, bdmu, bdsg, out);
}

// Round 3
// 134.612 us; speedup vs baseline: 1.2458x; 1.1176x over previous
//
#include <hip/hip_runtime.h>

// ---------------- problem constants ----------------
#define GRID_N   50
#define YDIM     2500      // 50*50
#define BATCH    16
#define NCTX     64
#define NTGT     128
#define BN       1024      // BATCH*NCTX
#define RDIM     128
#define ZDIM     64
#define HDIM     128
#define CCONV    32
#define NSTRIP   5         // 5 strips of 10 rows
#define STRIPROWS 10

typedef __attribute__((ext_vector_type(8))) short  s8v;   // 8 x bf16 (4 VGPR)
typedef __attribute__((ext_vector_type(4))) float  f4v;   // MFMA accum
typedef __attribute__((ext_vector_type(4))) unsigned int u4v;

__device__ __forceinline__ unsigned short f2bf(float f) {
    unsigned int u = __float_as_uint(f);
    u += 0x7FFFu + ((u >> 16) & 1u);
    return (unsigned short)(u >> 16);
}
__device__ __forceinline__ unsigned int cvtpk(float lo, float hi) {
    unsigned int r;
    asm("v_cvt_pk_bf16_f32 %0, %1, %2" : "=v"(r) : "v"(lo), "v"(hi));
    return r;
}

// ---------------- ws layout (bytes) ----------------
// w2p: 18432 @0 ; wdp: 1286144 @18432 ; part: 655360 @1304576 ;
// r_i: 524288 @1959936 ; zbuf: 4096 @2484224 ; h2d: 524288 @2488320 ;
// w1p: 2048 @3012608  -> total 3014656

// ---------------- k_conv smem layout ----------------
// h1: 312 rows x 128B (2 pos/row, 8 slots of 16B, XOR-swizzled) = 39936
#define PLB   39936        // planes base byte
#define PY    2            // y-plane elem base (within planes)
#define PX    738          // x-plane
#define P1    1490         // ones-plane
#define DUP   2228         // +1-shifted duplicate: pl[DUP+k] = pl[k+3]
#define OFFT  48848        // offtab (16 ints)
#define REDB  48912        // redbuf (128 floats)
#define SMEMB 49424

// =====================================================================
// pack w2 -> MFMA B frags (16x16x32) and w1(+b1) -> conv1 A frags (C^T)
// =====================================================================
__global__ void k_pack_w(const float* __restrict__ w1, const float* __restrict__ b1,
                         const float* __restrict__ w2,
                         unsigned short* __restrict__ w2p, unsigned short* __restrict__ w1p)
{
    int t = threadIdx.x;
    int l = t & 63, qq = t >> 6;
    int cout_lo = l & 15, cb = (l >> 4) & 3;
    for (int e = qq; e < 18; e += 4) {
        int tap = e >> 1, ntt = e & 1;
        int cout = ntt * 16 + cout_lo;
        unsigned int pk[4];
#pragma unroll
        for (int g = 0; g < 4; ++g) {
            int cin0 = cb * 8 + 2 * g;
            unsigned int lo = f2bf(w2[(cout * 32 + cin0) * 9 + tap]);
            unsigned int hi = f2bf(w2[(cout * 32 + cin0 + 1) * 9 + tap]);
            pk[g] = lo | (hi << 16);
        }
        uint4 o; o.x = pk[0]; o.y = pk[1]; o.z = pk[2]; o.w = pk[3];
        *(uint4*)&w2p[((tap * 2 + ntt) * 64 + l) * 8] = o;
    }
    if (t < 128) {
        int ct = t >> 6, lane = t & 63;
        int c = ct * 16 + (lane & 15), q2 = lane >> 4;
        // k-slot map: 0..8 = y tap, 16+t = x tap, 32 = bias(ones), -1 = zero
        const signed char kmap[32] = {0,1,3,4,6,7,16,17,  2,-1,5,-1,8,-1,18,-1,
                                      19,20,21,-1,22,23,24,-1, 32,-1,-1,-1,-1,-1,-1,-1};
        unsigned short v8[8];
#pragma unroll
        for (int j = 0; j < 8; ++j) {
            int km = kmap[q2 * 8 + j];
            float v = 0.f;
            if (km == 32) v = b1[c];
            else if (km >= 16) v = w1[(c * 2 + 1) * 9 + (km - 16)];
            else if (km >= 0) v = w1[(c * 2 + 0) * 9 + km];
            v8[j] = f2bf(v);
        }
        uint4 o;
        o.x = (unsigned)v8[0] | ((unsigned)v8[1] << 16);
        o.y = (unsigned)v8[2] | ((unsigned)v8[3] << 16);
        o.z = (unsigned)v8[4] | ((unsigned)v8[5] << 16);
        o.w = (unsigned)v8[6] | ((unsigned)v8[7] << 16);
        *(uint4*)&w1p[(ct * 64 + lane) * 8] = o;
    }
}

// =====================================================================
// pack Wdmu/Wdsig [128][2500] f32 -> B fragments bf16 (zero-padded tail)
// =====================================================================
__global__ void k_pack_wd(const float* __restrict__ Wmu, const float* __restrict__ Wsg,
                          unsigned short* __restrict__ wdp)
{
    int nt = blockIdx.x;          // 0..156
    int which = blockIdx.y;       // 0: mu, 1: sig
    const float* W = which ? Wsg : Wmu;
    unsigned short* outp = wdp + (size_t)which * (157 * 4 * 64 * 8);
    int t = threadIdx.x;
    int l = t & 63, ks = t >> 6;
    int n = nt * 16 + (l & 15);
    int kbase = ks * 32 + ((l >> 4) & 3) * 8;
    unsigned int pk[4];
#pragma unroll
    for (int g = 0; g < 4; ++g) {
        float f0 = (n < 2500) ? W[(kbase + 2 * g) * 2500 + n] : 0.f;
        float f1 = (n < 2500) ? W[(kbase + 2 * g + 1) * 2500 + n] : 0.f;
        pk[g] = (unsigned int)f2bf(f0) | ((unsigned int)f2bf(f1) << 16);
    }
    uint4 o; o.x = pk[0]; o.y = pk[1]; o.z = pk[2]; o.w = pk[3];
    *(uint4*)&outp[((nt * 4 + ks) * 64 + l) * 8] = o;
}

// =====================================================================
// conv1 + conv2 both bf16 MFMA implicit GEMM, fused relu+pool.
// h1 layout: row = pos>>1 (128B), slot8 = ((pos&1)<<2 | q) ^ ((pos>>1)&7),
// byte = (pos>>1)*128 + slot8*16  -- conflict-free (m201-style XOR8).
// conv2 is tap-outer: B-frags (w2p) re-loaded from L2 per tap (8 live regs).
// =====================================================================
__global__ __launch_bounds__(256, 3) void k_conv(
    const float* __restrict__ xc, const float* __restrict__ yc,
    const unsigned short* __restrict__ w1p, const unsigned short* __restrict__ w2p,
    const float* __restrict__ b2, float* __restrict__ part)
{
    __shared__ __align__(16) char smem[SMEMB];
    unsigned short* pl = (unsigned short*)(smem + PLB);
    int* offtab = (int*)(smem + OFFT);
    float* redbuf = (float*)(smem + REDB);

    const int t = threadIdx.x, lane = t & 63, w = t >> 6;
    const int l15 = lane & 15, q = lane >> 4;
    const int par = lane & 1;
    const int blk = blockIdx.x, s = blk / NSTRIP, strip = blk - s * NSTRIP;
    const int r0 = strip * STRIPROWS;

    const float xv = xc[s];
    const unsigned short xbf = f2bf(xv);
    const float b2v0 = b2[l15], b2v1 = b2[16 + l15];

    if (t < 16) {
        const int btab[16] = {1, 53, 105, 737,   3, 55, 107, 739,
                              789, 791, 841, 843,  P1, P1, P1, P1};
        offtab[t] = btab[t];
    }
    // fill planes (+ shifted dup). ry = e/52 via magic (valid e<736)
    for (int e = t; e < 736; e += 256) {
        unsigned ry = ((unsigned)(e * 1261)) >> 16;
        int ycol = e - (int)ry * 52;
        int gy = r0 - 2 + (int)ry, gc = ycol - 1;
        bool inb = ((unsigned)gy < 50u) && ((unsigned)gc < 50u);
        unsigned short yb = 0, xb = 0;
        if (inb) { yb = f2bf(yc[s * YDIM + gy * 50 + gc]); xb = xbf; }
        int s0 = PY + e, s1 = PX + e, s2 = P1 + e;
        pl[s0] = yb; if (s0 >= 3) pl[DUP + s0 - 3] = yb;
        pl[s1] = xb; pl[DUP + s1 - 3] = xb;
        pl[s2] = 0x3F80; pl[DUP + s2 - 3] = 0x3F80;
    }
    __syncthreads();

    // ---------------- conv1: M=624 (12x52 pos space), N=32, K=32 ----------------
    s8v w1f[2];
#pragma unroll
    for (int ct = 0; ct < 2; ++ct)
        w1f[ct] = *(const s8v*)&w1p[(ct * 64 + lane) * 8];
    int boff[4];
#pragma unroll
    for (int i = 0; i < 4; ++i) {
        int B = offtab[q * 4 + i];
        int pr = (B + lane) & 1;                       // m parity == lane&1
        boff[i] = PLB + ((pr ? (DUP - 3 + B) : B) << 1);
    }
    const f4v zf = {0.f, 0.f, 0.f, 0.f};
    for (int mt = w; mt < 39; mt += 4) {
        int m = mt * 16 + l15;
        int mb = m * 2;
        unsigned g0 = *(const unsigned*)(smem + boff[0] + mb);
        unsigned g1 = *(const unsigned*)(smem + boff[1] + mb);
        unsigned g2 = *(const unsigned*)(smem + boff[2] + mb);
        unsigned g3 = *(const unsigned*)(smem + boff[3] + mb);
        u4v gg = {g0, g1, g2, g3};
        s8v af = __builtin_bit_cast(s8v, gg);
        f4v c0 = __builtin_amdgcn_mfma_f32_16x16x32_bf16(w1f[0], af, zf, 0, 0, 0);
        f4v c1 = __builtin_amdgcn_mfma_f32_16x16x32_bf16(w1f[1], af, zf, 0, 0, 0);
        unsigned mr = ((unsigned)(m * 1261)) >> 16;     // m/52
        int mc = m - (int)mr * 52;
        int gy = r0 - 1 + (int)mr;
        bool valid = ((unsigned)(mc - 1) < 50u) && ((unsigned)gy < 50u);
        unsigned p0 = cvtpk(fmaxf(c0[0], 0.f), fmaxf(c0[1], 0.f));
        unsigned p1 = cvtpk(fmaxf(c0[2], 0.f), fmaxf(c0[3], 0.f));
        unsigned p2 = cvtpk(fmaxf(c1[0], 0.f), fmaxf(c1[1], 0.f));
        unsigned p3 = cvtpk(fmaxf(c1[2], 0.f), fmaxf(c1[3], 0.f));
        if (!valid) { p0 = 0u; p1 = 0u; p2 = 0u; p3 = 0u; }
        // swizzled write: lane holds cin [q*4, q*4+4) (ct=0) and +16 (ct=1)
        int rrow = m >> 1;
        int modd4 = (m & 1) << 2;
        int r7 = rrow & 7;
        char* base = smem + (rrow << 7) + ((q & 1) << 3);
        int s0w = ((modd4 | (q >> 1)) ^ r7) << 4;
        int s1w = ((modd4 | (2 + (q >> 1))) ^ r7) << 4;
        *(uint2*)(base + s0w) = make_uint2(p0, p1);
        *(uint2*)(base + s1w) = make_uint2(p2, p3);
    }
    __syncthreads();

    // ---------------- conv2: M=512(pad), N=32, K=288, tap-outer ----------------
    f4v acc[8][2];
#pragma unroll
    for (int i = 0; i < 8; ++i) { acc[i][0] = zf; acc[i][1] = zf; }
    int u_[8], up_[8];
#pragma unroll
    for (int tt = 0; tt < 8; ++tt) {
        int m2 = (w * 8 + tt) * 16 + l15;
        unsigned orr = ((unsigned)(m2 * 1311)) >> 16;   // m2/50
        int pc = m2 + 2 * (int)orr;                     // pos of output m2
        u_[tt] = pc >> 1;
        up_[tt] = u_[tt] + par;
    }
    const int oq  = (par << 2) | q;        // (pos&1)<<2 | q for kx in {0,2}
    const int oqx = ((par ^ 1) << 2) | q;  // for kx == 1
#pragma unroll
    for (int tp = 0; tp < 9; ++tp) {
        const int ky = tp / 3, kx = tp % 3;
        s8v b0 = *(const s8v*)&w2p[((tp * 2 + 0) * 64 + lane) * 8];
        s8v b1 = *(const s8v*)&w2p[((tp * 2 + 1) * 64 + lane) * 8];
#pragma unroll
        for (int tt = 0; tt < 8; ++tt) {
            int r = (kx == 1 ? up_[tt] : u_[tt]) + 26 * ky + (kx == 2 ? 1 : 0);
            int so = ((kx == 1 ? oqx : oq) ^ (r & 7)) << 4;
            s8v a = *(const s8v*)(smem + (r << 7) + so);
            acc[tt][0] = __builtin_amdgcn_mfma_f32_16x16x32_bf16(a, b0, acc[tt][0], 0, 0, 0);
            acc[tt][1] = __builtin_amdgcn_mfma_f32_16x16x32_bf16(a, b1, acc[tt][1], 0, 0, 0);
        }
    }
    // fused bias + relu + spatial partial sum
    float ps0 = 0.f, ps1 = 0.f;
#pragma unroll
    for (int tt = 0; tt < 8; ++tt) {
        int mbase = (w * 8 + tt) * 16 + q * 4;
#pragma unroll
        for (int r = 0; r < 4; ++r) {
            if (mbase + r < 500) {
                ps0 += fmaxf(acc[tt][0][r] + b2v0, 0.f);
                ps1 += fmaxf(acc[tt][1][r] + b2v1, 0.f);
            }
        }
    }
    ps0 += __shfl_xor(ps0, 16); ps0 += __shfl_xor(ps0, 32);
    ps1 += __shfl_xor(ps1, 16); ps1 += __shfl_xor(ps1, 32);
    if (lane < 16) {
        redbuf[w * 32 + l15] = ps0;
        redbuf[w * 32 + 16 + l15] = ps1;
    }
    __syncthreads();
    if (t < 32)
        part[(s * NSTRIP + strip) * 32 + t] =
            redbuf[t] + redbuf[32 + t] + redbuf[64 + t] + redbuf[96 + t];
}

// =====================================================================
// per-sample encoder MLP: pooled -> relu(feat@We1) -> r_i
// =====================================================================
__global__ void k_enc(const float* __restrict__ part, const float* __restrict__ xc,
                      const float* __restrict__ We1, const float* __restrict__ be1,
                      const float* __restrict__ We2, const float* __restrict__ be2,
                      float* __restrict__ r_i)
{
    __shared__ float feat[33];
    __shared__ float h[128];
    int s = blockIdx.x, j = threadIdx.x;
    if (j < 32) {
        float v = 0.f;
#pragma unroll
        for (int st = 0; st < NSTRIP; ++st) v += part[(s * NSTRIP + st) * 32 + j];
        feat[j] = v * (1.f / 2500.f);
    }
    if (j == 0) feat[32] = xc[s];
    __syncthreads();
    float a = be1[j];
#pragma unroll 4
    for (int k = 0; k < 33; ++k) a = fmaf(feat[k], We1[k * 128 + j], a);
    h[j] = fmaxf(a, 0.f);
    __syncthreads();
    float r = be2[j];
#pragma unroll 8
    for (int k = 0; k < 128; ++k) r = fmaf(h[k], We2[k * 128 + j], r);
    r_i[s * 128 + j] = r;
}

// =====================================================================
// aggregate r over context, mu/sigma encoder, z = mu + sigma*eps (256 thr)
// =====================================================================
__global__ void k_ms(const float* __restrict__ r_i,
                     const float* __restrict__ Wh, const float* __restrict__ bh,
                     const float* __restrict__ Wmu, const float* __restrict__ bmu,
                     const float* __restrict__ Wsig, const float* __restrict__ bsig,
                     const float* __restrict__ eps, float* __restrict__ out,
                     float* __restrict__ zbuf)
{
    __shared__ float r[128], hr[128], tmp[2][128];
    int b = blockIdx.x, t = threadIdx.x;
    int j = t & 127, g = t >> 7;
    float acc = 0.f;
#pragma unroll 4
    for (int i = g; i < NCTX; i += 2) acc += r_i[(b * NCTX + i) * 128 + j];
    tmp[g][j] = acc;
    __syncthreads();
    if (g == 0) r[j] = (tmp[0][j] + tmp[1][j]) * (1.f / 64.f);
    __syncthreads();
    float a = (g == 0) ? bh[j] : 0.f;
#pragma unroll 8
    for (int k = g * 64; k < g * 64 + 64; ++k) a = fmaf(r[k], Wh[k * 128 + j], a);
    tmp[g][j] = a;
    __syncthreads();
    if (g == 0) hr[j] = fmaxf(tmp[0][j] + tmp[1][j], 0.f);
    __syncthreads();
    if (j < 64) {
        float m = (g == 0) ? bmu[j] : 0.f, sg = (g == 0) ? bsig[j] : 0.f;
#pragma unroll 8
        for (int k = g * 64; k < g * 64 + 64; ++k) {
            m  = fmaf(hr[k], Wmu[k * 64 + j], m);
            sg = fmaf(hr[k], Wsig[k * 64 + j], sg);
        }
        tmp[g][j] = m; tmp[g][64 + j] = sg;
    }
    __syncthreads();
    if (t < 64) {
        float m  = tmp[0][t] + tmp[1][t];
        float sg = tmp[0][64 + t] + tmp[1][64 + t];
        float sig = 0.1f + 0.9f / (1.f + expf(-sg));
        out[10240000 + b * 64 + t] = m;      // mu_c
        out[10241024 + b * 64 + t] = sig;    // sigma_c
        zbuf[b * 64 + t] = m + sig * eps[b * 64 + t];
    }
}

// =====================================================================
// decoder hidden: 512 blocks x 256 thr, 4 rows/block (2 per half-group)
// =====================================================================
__global__ __launch_bounds__(256) void k_dec1(
    const float* __restrict__ xt, const float* __restrict__ zbuf,
    const float* __restrict__ Wd1, const float* __restrict__ bd1,
    const float* __restrict__ Wd2, const float* __restrict__ bd2,
    unsigned short* __restrict__ h2d)
{
    __shared__ float zsh[64];
    __shared__ float vsh[2][128];
    __shared__ float h1sh[4][128];
    int t = threadIdx.x;
    int j = t & 127, g = t >> 7;
    int r0 = blockIdx.x * 4;
    int b = r0 >> 7;
    if (t < 64) zsh[t] = zbuf[b * 64 + t];
    __syncthreads();
    float v = (g == 0) ? bd1[j] : 0.f;
#pragma unroll 8
    for (int k = g * 32; k < g * 32 + 32; ++k)
        v = fmaf(zsh[k], Wd1[(1 + k) * 128 + j], v);
    vsh[g][j] = v;
    __syncthreads();
    float vv = vsh[0][j] + vsh[1][j];
    float w0 = Wd1[j];
    int ra = r0 + g * 2;
    float x0 = xt[ra], x1 = xt[ra + 1];
    h1sh[g * 2][j]     = fmaxf(fmaf(x0, w0, vv), 0.f);
    h1sh[g * 2 + 1][j] = fmaxf(fmaf(x1, w0, vv), 0.f);
    __syncthreads();
    float bd2j = bd2[j];
    float a0 = bd2j, a1 = bd2j;
#pragma unroll 8
    for (int k = 0; k < 128; ++k) {
        float wv = Wd2[k * 128 + j];
        a0 = fmaf(h1sh[g * 2][k], wv, a0);
        a1 = fmaf(h1sh[g * 2 + 1][k], wv, a1);
    }
    h2d[(size_t)ra * 128 + j]       = f2bf(fmaxf(a0, 0.f));
    h2d[(size_t)(ra + 1) * 128 + j] = f2bf(fmaxf(a1, 0.f));
}

// =====================================================================
// big decoder GEMM: [2048,128] @ [128,2500] (x2 heads), fused epilogue
// =====================================================================
__global__ __launch_bounds__(256) void k_gemm(
    const unsigned short* __restrict__ h2d, const unsigned short* __restrict__ wdp,
    const float* __restrict__ bdmu, const float* __restrict__ bdsg,
    float* __restrict__ out)
{
    __shared__ __align__(16) unsigned short Al[64 * 128];
    int t = threadIdx.x, lane = t & 63, w = t >> 6;
    int m0 = blockIdx.x * 64;
    int which = blockIdx.z;
#pragma unroll
    for (int i = 0; i < 4; ++i) {
        int g = t + i * 256;
        int row = g >> 4, bk = g & 15;
        uint4 v = *(const uint4*)&h2d[(size_t)(m0 + row) * 128 + bk * 8];
        *(uint4*)&Al[row * 128 + ((bk ^ (row & 7)) << 3)] = v;
    }
    __syncthreads();
    int nt = blockIdx.y * 4 + w;
    if (nt < 157) {
        const unsigned short* wp = wdp + (size_t)which * (157 * 4 * 64 * 8);
        s8v bfr[4];
#pragma unroll
        for (int ks = 0; ks < 4; ++ks)
            bfr[ks] = *(const s8v*)&wp[((nt * 4 + ks) * 64 + lane) * 8];
        f4v acc[4];
        {
            f4v zf = {0.f, 0.f, 0.f, 0.f};
#pragma unroll
            for (int mt = 0; mt < 4; ++mt) acc[mt] = zf;
        }
        int lcol = lane & 15, lq = lane >> 4;
#pragma unroll
        for (int mt = 0; mt < 4; ++mt) {
            int mrow = mt * 16 + lcol;
#pragma unroll
            for (int ks = 0; ks < 4; ++ks) {
                int bk = ks * 4 + lq;
                s8v a = *(const s8v*)&Al[mrow * 128 + ((bk ^ (mrow & 7)) << 3)];
                acc[mt] = __builtin_amdgcn_mfma_f32_16x16x32_bf16(a, bfr[ks], acc[mt], 0, 0, 0);
            }
        }
        int col = nt * 16 + lcol;
        if (col < 2500) {
            const float* bp = which ? bdsg : bdmu;
            float bv = bp[col];
            size_t zoff = (size_t)which * 5120000;
#pragma unroll
            for (int mt = 0; mt < 4; ++mt)
#pragma unroll
                for (int r = 0; r < 4; ++r) {
                    int row = m0 + mt * 16 + lq * 4 + r;
                    float vv = acc[mt][r] + bv;
                    if (which) {
                        float sp = fmaxf(vv, 0.f) + log1pf(expf(-fabsf(vv)));
                        vv = 0.1f + 0.9f * sp;
                    }
                    out[zoff + (size_t)row * 2500 + col] = vv;
                }
        }
    }
}

// =====================================================================
extern "C" void kernel_launch(void* const* d_in, const int* in_sizes, int n_in,
                              void* d_out, int out_size, void* d_ws, size_t ws_size,
                              hipStream_t stream)
{
    const float* xc   = (const float*)d_in[0];
    const float* yc   = (const float*)d_in[1];
    const float* xt   = (const float*)d_in[2];
    const float* eps  = (const float*)d_in[3];
    const float* w1   = (const float*)d_in[4];
    const float* b1   = (const float*)d_in[5];
    const float* w2   = (const float*)d_in[6];
    const float* b2   = (const float*)d_in[7];
    const float* We1  = (const float*)d_in[8];
    const float* be1  = (const float*)d_in[9];
    const float* We2  = (const float*)d_in[10];
    const float* be2  = (const float*)d_in[11];
    const float* Wh   = (const float*)d_in[12];
    const float* bh   = (const float*)d_in[13];
    const float* Wmu  = (const float*)d_in[14];
    const float* bmu  = (const float*)d_in[15];
    const float* Wsig = (const float*)d_in[16];
    const float* bsig = (const float*)d_in[17];
    const float* Wd1  = (const float*)d_in[18];
    const float* bd1  = (const float*)d_in[19];
    const float* Wd2  = (const float*)d_in[20];
    const float* bd2  = (const float*)d_in[21];
    const float* Wdmu = (const float*)d_in[22];
    const float* bdmu = (const float*)d_in[23];
    const float* Wdsg = (const float*)d_in[24];
    const float* bdsg = (const float*)d_in[25];

    float* out = (float*)d_out;
    char* wsb  = (char*)d_ws;
    unsigned short* w2p = (unsigned short*)(wsb + 0);
    unsigned short* wdp = (unsigned short*)(wsb + 18432);
    float* part = (float*)(wsb + 1304576);
    float* r_i  = (float*)(wsb + 1959936);
    float* zbuf = (float*)(wsb + 2484224);
    unsigned short* h2d = (unsigned short*)(wsb + 2488320);
    unsigned short* w1p = (unsigned short*)(wsb + 3012608);

    hipLaunchKernelGGL(k_pack_w, dim3(1), dim3(256), 0, stream, w1, b1, w2, w2p, w1p);
    hipLaunchKernelGGL(k_pack_wd, dim3(157, 2), dim3(256), 0, stream, Wdmu, Wdsg, wdp);
    hipLaunchKernelGGL(k_conv, dim3(BN * NSTRIP), dim3(256), 0, stream,
                       xc, yc, w1p, w2p, b2, part);
    hipLaunchKernelGGL(k_enc, dim3(BN), dim3(128), 0, stream,
                       part, xc, We1, be1, We2, be2, r_i);
    hipLaunchKernelGGL(k_ms, dim3(BATCH), dim3(256), 0, stream,
                       r_i, Wh, bh, Wmu, bmu, Wsig, bsig, eps, out, zbuf);
    hipLaunchKernelGGL(k_dec1, dim3(512), dim3(256), 0, stream,
                       xt, zbuf, Wd1, bd1, Wd2, bd2, h2d);
    hipLaunchKernelGGL(k_gemm, dim3(32, 40, 2), dim3(256), 0, stream,
                       h2d, wdp, bdmu, bdsg, out);
}

// Round 4
// 118.056 us; speedup vs baseline: 1.4205x; 1.1402x over previous
//
#include <hip/hip_runtime.h>

// ---------------- problem constants ----------------
#define GRID_N   50
#define YDIM     2500      // 50*50
#define BATCH    16
#define NCTX     64
#define NTGT     128
#define BN       1024      // BATCH*NCTX
#define RDIM     128
#define ZDIM     64
#define HDIM     128
#define CCONV    32
#define NSTRIP   5         // 5 strips of 10 rows
#define STRIPROWS 10

typedef __attribute__((ext_vector_type(8))) short  s8v;   // 8 x bf16 (4 VGPR)
typedef __attribute__((ext_vector_type(4))) float  f4v;   // MFMA accum
typedef __attribute__((ext_vector_type(4))) unsigned int u4v;

__device__ __forceinline__ unsigned short f2bf(float f) {
    unsigned int u = __float_as_uint(f);
    u += 0x7FFFu + ((u >> 16) & 1u);
    return (unsigned short)(u >> 16);
}
__device__ __forceinline__ unsigned int cvtpk(float lo, float hi) {
    unsigned int r;
    asm("v_cvt_pk_bf16_f32 %0, %1, %2" : "=v"(r) : "v"(lo), "v"(hi));
    return r;
}

// ---------------- ws layout (bytes) ----------------
// w2p: 18432 @0 ; wdp: 1286144 @18432 ; part: 655360 @1304576 ;
// r_i: 524288 @1959936 ; zbuf: 4096 @2484224 ; h2d: 524288 @2488320 ;
// w1p: 2048 @3012608  -> total 3014656

// ---------------- k_conv smem layout (39936 B total = 4 blocks/CU) ----
// h1: 312 rows x 128B (2 pos/row, 8 slots of 16B, XOR-swizzled)
// planes ALIASED into h1 tail [31024, 39936): live only during conv1;
// h1 rows >= 242 (pos >= 484) are written in phase B after planes die.
// redbuf aliases h1[0..512) after a post-conv2 barrier.
#define PLB   31024        // plane region base byte
#define PY    2            // y-plane elem base (within planes)
#define PX    738          // x-plane
#define P1    1490         // ones-plane
#define DUP   2228         // +1-shifted duplicate: pl[DUP+k] = pl[k+3]
#define SMEMB 39936

// K-permutation for conv2 (shared by h1 slot-groups and w2p pack):
// k-slot (q*8+j) <-> cin = (j<4) ? q*4+j : 16+q*4+(j-4)

// =====================================================================
// merged pack kernel: y<2 -> Wdmu/Wdsig frags ; y==2,x==0 -> w1p/w2p
// =====================================================================
__global__ void k_pack(const float* __restrict__ w1, const float* __restrict__ b1,
                       const float* __restrict__ w2,
                       unsigned short* __restrict__ w2p, unsigned short* __restrict__ w1p,
                       const float* __restrict__ Wmu, const float* __restrict__ Wsg,
                       unsigned short* __restrict__ wdp)
{
    int t = threadIdx.x;
    if (blockIdx.y == 2) {
        if (blockIdx.x != 0) return;
        int l = t & 63, qq = t >> 6;
        int cout_lo = l & 15, cb = (l >> 4) & 3;
        for (int e = qq; e < 18; e += 4) {
            int tap = e >> 1, ntt = e & 1;
            int cout = ntt * 16 + cout_lo;
            unsigned int pk[4];
#pragma unroll
            for (int g = 0; g < 4; ++g) {
                int jj = 2 * g;
                int cinL = (jj < 4) ? (cb * 4 + jj) : (16 + cb * 4 + (jj - 4));
                unsigned int lo = f2bf(w2[(cout * 32 + cinL) * 9 + tap]);
                unsigned int hi = f2bf(w2[(cout * 32 + cinL + 1) * 9 + tap]);
                pk[g] = lo | (hi << 16);
            }
            uint4 o; o.x = pk[0]; o.y = pk[1]; o.z = pk[2]; o.w = pk[3];
            *(uint4*)&w2p[((tap * 2 + ntt) * 64 + l) * 8] = o;
        }
        if (t < 128) {
            int ct = t >> 6, lane = t & 63;
            int c = ct * 16 + (lane & 15), q2 = lane >> 4;
            const signed char kmap[32] = {0,1,3,4,6,7,16,17,  2,-1,5,-1,8,-1,18,-1,
                                          19,20,21,-1,22,23,24,-1, 32,-1,-1,-1,-1,-1,-1,-1};
            unsigned short v8[8];
#pragma unroll
            for (int j = 0; j < 8; ++j) {
                int km = kmap[q2 * 8 + j];
                float v = 0.f;
                if (km == 32) v = b1[c];
                else if (km >= 16) v = w1[(c * 2 + 1) * 9 + (km - 16)];
                else if (km >= 0) v = w1[(c * 2 + 0) * 9 + km];
                v8[j] = f2bf(v);
            }
            uint4 o;
            o.x = (unsigned)v8[0] | ((unsigned)v8[1] << 16);
            o.y = (unsigned)v8[2] | ((unsigned)v8[3] << 16);
            o.z = (unsigned)v8[4] | ((unsigned)v8[5] << 16);
            o.w = (unsigned)v8[6] | ((unsigned)v8[7] << 16);
            *(uint4*)&w1p[(ct * 64 + lane) * 8] = o;
        }
        return;
    }
    // ---- Wd pack ----
    int nt = blockIdx.x;          // 0..156
    int which = blockIdx.y;       // 0: mu, 1: sig
    const float* W = which ? Wsg : Wmu;
    unsigned short* outp = wdp + (size_t)which * (157 * 4 * 64 * 8);
    int l = t & 63, ks = t >> 6;
    int n = nt * 16 + (l & 15);
    int kbase = ks * 32 + ((l >> 4) & 3) * 8;
    unsigned int pk[4];
#pragma unroll
    for (int g = 0; g < 4; ++g) {
        float f0 = (n < 2500) ? W[(kbase + 2 * g) * 2500 + n] : 0.f;
        float f1 = (n < 2500) ? W[(kbase + 2 * g + 1) * 2500 + n] : 0.f;
        pk[g] = (unsigned int)f2bf(f0) | ((unsigned int)f2bf(f1) << 16);
    }
    uint4 o; o.x = pk[0]; o.y = pk[1]; o.z = pk[2]; o.w = pk[3];
    *(uint4*)&outp[((nt * 4 + ks) * 64 + l) * 8] = o;
}

// =====================================================================
// conv1 + conv2 both bf16 MFMA implicit GEMM, fused relu+pool.
// =====================================================================
__global__ __launch_bounds__(256, 4) void k_conv(
    const float* __restrict__ xc, const float* __restrict__ yc,
    const unsigned short* __restrict__ w1p, const unsigned short* __restrict__ w2p,
    const float* __restrict__ b2, float* __restrict__ part)
{
    __shared__ __align__(16) char smem[SMEMB];
    unsigned short* pl = (unsigned short*)(smem + PLB);
    float* redbuf = (float*)smem;   // alias, used after post-conv2 barrier

    const int t = threadIdx.x, lane = t & 63, w = t >> 6;
    const int l15 = lane & 15, q = lane >> 4;
    const int par = lane & 1;
    const int blk = blockIdx.x, s = blk / NSTRIP, strip = blk - s * NSTRIP;
    const int r0 = strip * STRIPROWS;

    const float xv = xc[s];
    const unsigned short xbf = f2bf(xv);
    const float b2v0 = b2[l15], b2v1 = b2[16 + l15];

    // fill planes (+ shifted dup). ry = e/52 via magic (valid e<736)
    for (int e = t; e < 736; e += 256) {
        unsigned ry = ((unsigned)(e * 1261)) >> 16;
        int ycol = e - (int)ry * 52;
        int gy = r0 - 2 + (int)ry, gc = ycol - 1;
        bool inb = ((unsigned)gy < 50u) && ((unsigned)gc < 50u);
        unsigned short yb = 0, xb = 0;
        if (inb) { yb = f2bf(yc[s * YDIM + gy * 50 + gc]); xb = xbf; }
        int s0 = PY + e, s1 = PX + e, s2 = P1 + e;
        pl[s0] = yb; if (s0 >= 3) pl[DUP + s0 - 3] = yb;
        pl[s1] = xb; pl[DUP + s1 - 3] = xb;
        pl[s2] = 0x3F80; pl[DUP + s2 - 3] = 0x3F80;
    }

    // conv1 weight fragments (L2-resident)
    s8v w1f[2];
#pragma unroll
    for (int ct = 0; ct < 2; ++ct)
        w1f[ct] = *(const s8v*)&w1p[(ct * 64 + lane) * 8];

    // per-thread plane tap bases (no LDS table)
    int B0 = (q == 0) ? 1 : (q == 1) ? 3 : (q == 2) ? 789 : P1;
    int B1 = (q < 2) ? (B0 + 52)  : ((q == 2) ? 791 : P1);
    int B2 = (q < 2) ? (B0 + 104) : ((q == 2) ? 841 : P1);
    int B3 = (q < 2) ? (B0 + 736) : ((q == 2) ? 843 : P1);
    auto mkoff = [&](int B) {
        int pr = (B + lane) & 1;
        return PLB + ((pr ? (DUP - 3 + B) : B) << 1);
    };
    const int bo0 = mkoff(B0), bo1 = mkoff(B1), bo2 = mkoff(B2), bo3 = mkoff(B3);

    __syncthreads();

    const f4v zf = {0.f, 0.f, 0.f, 0.f};
    // ---------------- conv1: M=624 (12x52 pos space), N=32, K=32 ----------------
    auto do_tile = [&](int mt) -> uint4 {
        int m = mt * 16 + l15;
        int mb = m * 2;
        unsigned g0 = *(const unsigned*)(smem + bo0 + mb);
        unsigned g1 = *(const unsigned*)(smem + bo1 + mb);
        unsigned g2 = *(const unsigned*)(smem + bo2 + mb);
        unsigned g3 = *(const unsigned*)(smem + bo3 + mb);
        u4v gg = {g0, g1, g2, g3};
        s8v af = __builtin_bit_cast(s8v, gg);
        f4v c0 = __builtin_amdgcn_mfma_f32_16x16x32_bf16(w1f[0], af, zf, 0, 0, 0);
        f4v c1 = __builtin_amdgcn_mfma_f32_16x16x32_bf16(w1f[1], af, zf, 0, 0, 0);
        unsigned mr = ((unsigned)(m * 1261)) >> 16;     // m/52
        int mc = m - (int)mr * 52;
        int gy = r0 - 1 + (int)mr;
        bool valid = ((unsigned)(mc - 1) < 50u) && ((unsigned)gy < 50u);
        unsigned p0 = cvtpk(fmaxf(c0[0], 0.f), fmaxf(c0[1], 0.f));
        unsigned p1 = cvtpk(fmaxf(c0[2], 0.f), fmaxf(c0[3], 0.f));
        unsigned p2 = cvtpk(fmaxf(c1[0], 0.f), fmaxf(c1[1], 0.f));
        unsigned p3 = cvtpk(fmaxf(c1[2], 0.f), fmaxf(c1[3], 0.f));
        if (!valid) { p0 = 0u; p1 = 0u; p2 = 0u; p3 = 0u; }
        return make_uint4(p0, p1, p2, p3);
    };
    auto wr_tile = [&](int mt, uint4 v) {
        int m = mt * 16 + l15;
        int rrow = m >> 1;
        int slot = (((m & 1) << 2) | q) ^ (rrow & 7);
        *(uint4*)(smem + (rrow << 7) + (slot << 4)) = v;
    };

    // phase A: tiles 0..29 (write region disjoint from planes)
#pragma unroll
    for (int it = 0; it < 8; ++it) {
        int mt = w + it * 4;
        if (mt <= 29) {
            uint4 v = do_tile(mt);
            wr_tile(mt, v);
        }
    }
    // held tiles 30..38 (write bytes overlap planes -> hold in regs)
    {
        int mt0 = (w >= 2) ? (28 + w) : (32 + w);
        uint4 hA = do_tile(mt0);
        uint4 hB = do_tile(mt0 + 4);
        uint4 hC = make_uint4(0u, 0u, 0u, 0u);
        bool third = (w == 2);
        if (third) hC = do_tile(38);
        __syncthreads();                 // planes dead from here
        wr_tile(mt0, hA);
        wr_tile(mt0 + 4, hB);
        if (third) wr_tile(38, hC);
    }
    __syncthreads();

    // ---------------- conv2: M=512(pad), N=32, K=288, tap-outer ----------------
    f4v acc[8][2];
#pragma unroll
    for (int i = 0; i < 8; ++i) { acc[i][0] = zf; acc[i][1] = zf; }
    int u_[8], up_[8];
#pragma unroll
    for (int tt = 0; tt < 8; ++tt) {
        int m2 = (w * 8 + tt) * 16 + l15;
        unsigned orr = ((unsigned)(m2 * 1311)) >> 16;   // m2/50
        int pc = m2 + 2 * (int)orr;                     // pos of output m2
        int u = pc >> 1;
        u = (u > 258) ? 258 : u;                        // keep padded lanes in-bounds
        u_[tt] = u;
        up_[tt] = u + par;
    }
    const int oq  = (par << 2) | q;        // (pos&1)<<2 | q for kx in {0,2}
    const int oqx = ((par ^ 1) << 2) | q;  // for kx == 1
    __builtin_amdgcn_s_setprio(1);
#pragma unroll
    for (int tp = 0; tp < 9; ++tp) {
        const int ky = tp / 3, kx = tp % 3;
        s8v b0 = *(const s8v*)&w2p[((tp * 2 + 0) * 64 + lane) * 8];
        s8v b1 = *(const s8v*)&w2p[((tp * 2 + 1) * 64 + lane) * 8];
#pragma unroll
        for (int tt = 0; tt < 8; ++tt) {
            int r = (kx == 1 ? up_[tt] : u_[tt]) + 26 * ky + (kx == 2 ? 1 : 0);
            int so = ((kx == 1 ? oqx : oq) ^ (r & 7)) << 4;
            s8v a = *(const s8v*)(smem + (r << 7) + so);
            acc[tt][0] = __builtin_amdgcn_mfma_f32_16x16x32_bf16(a, b0, acc[tt][0], 0, 0, 0);
            acc[tt][1] = __builtin_amdgcn_mfma_f32_16x16x32_bf16(a, b1, acc[tt][1], 0, 0, 0);
        }
    }
    __builtin_amdgcn_s_setprio(0);

    // fused bias + relu + spatial partial sum (only tile 31 has rows >= 500)
    float ps0 = 0.f, ps1 = 0.f;
#pragma unroll
    for (int tt = 0; tt < 8; ++tt) {
        int tile = w * 8 + tt;             // wave-uniform
        if (tile != 31) {
#pragma unroll
            for (int r = 0; r < 4; ++r) {
                ps0 += fmaxf(acc[tt][0][r] + b2v0, 0.f);
                ps1 += fmaxf(acc[tt][1][r] + b2v1, 0.f);
            }
        } else {
            int mbase = tile * 16 + q * 4;
#pragma unroll
            for (int r = 0; r < 4; ++r) {
                if (mbase + r < 500) {
                    ps0 += fmaxf(acc[tt][0][r] + b2v0, 0.f);
                    ps1 += fmaxf(acc[tt][1][r] + b2v1, 0.f);
                }
            }
        }
    }
    ps0 += __shfl_xor(ps0, 16); ps0 += __shfl_xor(ps0, 32);
    ps1 += __shfl_xor(ps1, 16); ps1 += __shfl_xor(ps1, 32);
    __syncthreads();                       // all conv2 h1 reads done -> redbuf alias safe
    if (lane < 16) {
        redbuf[w * 32 + l15] = ps0;
        redbuf[w * 32 + 16 + l15] = ps1;
    }
    __syncthreads();
    if (t < 32)
        part[(s * NSTRIP + strip) * 32 + t] =
            redbuf[t] + redbuf[32 + t] + redbuf[64 + t] + redbuf[96 + t];
}

// =====================================================================
// per-sample encoder MLP: pooled -> relu(feat@We1) -> r_i
// =====================================================================
__global__ void k_enc(const float* __restrict__ part, const float* __restrict__ xc,
                      const float* __restrict__ We1, const float* __restrict__ be1,
                      const float* __restrict__ We2, const float* __restrict__ be2,
                      float* __restrict__ r_i)
{
    __shared__ float feat[33];
    __shared__ float h[128];
    int s = blockIdx.x, j = threadIdx.x;
    if (j < 32) {
        float v = 0.f;
#pragma unroll
        for (int st = 0; st < NSTRIP; ++st) v += part[(s * NSTRIP + st) * 32 + j];
        feat[j] = v * (1.f / 2500.f);
    }
    if (j == 0) feat[32] = xc[s];
    __syncthreads();
    float a = be1[j];
#pragma unroll 4
    for (int k = 0; k < 33; ++k) a = fmaf(feat[k], We1[k * 128 + j], a);
    h[j] = fmaxf(a, 0.f);
    __syncthreads();
    float r = be2[j];
#pragma unroll 8
    for (int k = 0; k < 128; ++k) r = fmaf(h[k], We2[k * 128 + j], r);
    r_i[s * 128 + j] = r;
}

// =====================================================================
// aggregate r over context, mu/sigma encoder, z = mu + sigma*eps (256 thr)
// =====================================================================
__global__ void k_ms(const float* __restrict__ r_i,
                     const float* __restrict__ Wh, const float* __restrict__ bh,
                     const float* __restrict__ Wmu, const float* __restrict__ bmu,
                     const float* __restrict__ Wsig, const float* __restrict__ bsig,
                     const float* __restrict__ eps, float* __restrict__ out,
                     float* __restrict__ zbuf)
{
    __shared__ float r[128], hr[128], tmp[2][128];
    int b = blockIdx.x, t = threadIdx.x;
    int j = t & 127, g = t >> 7;
    float acc = 0.f;
#pragma unroll 4
    for (int i = g; i < NCTX; i += 2) acc += r_i[(b * NCTX + i) * 128 + j];
    tmp[g][j] = acc;
    __syncthreads();
    if (g == 0) r[j] = (tmp[0][j] + tmp[1][j]) * (1.f / 64.f);
    __syncthreads();
    float a = (g == 0) ? bh[j] : 0.f;
#pragma unroll 8
    for (int k = g * 64; k < g * 64 + 64; ++k) a = fmaf(r[k], Wh[k * 128 + j], a);
    tmp[g][j] = a;
    __syncthreads();
    if (g == 0) hr[j] = fmaxf(tmp[0][j] + tmp[1][j], 0.f);
    __syncthreads();
    if (j < 64) {
        float m = (g == 0) ? bmu[j] : 0.f, sg = (g == 0) ? bsig[j] : 0.f;
#pragma unroll 8
        for (int k = g * 64; k < g * 64 + 64; ++k) {
            m  = fmaf(hr[k], Wmu[k * 64 + j], m);
            sg = fmaf(hr[k], Wsig[k * 64 + j], sg);
        }
        tmp[g][j] = m; tmp[g][64 + j] = sg;
    }
    __syncthreads();
    if (t < 64) {
        float m  = tmp[0][t] + tmp[1][t];
        float sg = tmp[0][64 + t] + tmp[1][64 + t];
        float sig = 0.1f + 0.9f / (1.f + expf(-sg));
        out[10240000 + b * 64 + t] = m;      // mu_c
        out[10241024 + b * 64 + t] = sig;    // sigma_c
        zbuf[b * 64 + t] = m + sig * eps[b * 64 + t];
    }
}

// =====================================================================
// decoder hidden: 512 blocks x 256 thr, 4 rows/block (2 per half-group)
// =====================================================================
__global__ __launch_bounds__(256) void k_dec1(
    const float* __restrict__ xt, const float* __restrict__ zbuf,
    const float* __restrict__ Wd1, const float* __restrict__ bd1,
    const float* __restrict__ Wd2, const float* __restrict__ bd2,
    unsigned short* __restrict__ h2d)
{
    __shared__ float zsh[64];
    __shared__ float vsh[2][128];
    __shared__ float h1sh[4][128];
    int t = threadIdx.x;
    int j = t & 127, g = t >> 7;
    int r0 = blockIdx.x * 4;
    int b = r0 >> 7;
    if (t < 64) zsh[t] = zbuf[b * 64 + t];
    __syncthreads();
    float v = (g == 0) ? bd1[j] : 0.f;
#pragma unroll 8
    for (int k = g * 32; k < g * 32 + 32; ++k)
        v = fmaf(zsh[k], Wd1[(1 + k) * 128 + j], v);
    vsh[g][j] = v;
    __syncthreads();
    float vv = vsh[0][j] + vsh[1][j];
    float w0 = Wd1[j];
    int ra = r0 + g * 2;
    float x0 = xt[ra], x1 = xt[ra + 1];
    h1sh[g * 2][j]     = fmaxf(fmaf(x0, w0, vv), 0.f);
    h1sh[g * 2 + 1][j] = fmaxf(fmaf(x1, w0, vv), 0.f);
    __syncthreads();
    float bd2j = bd2[j];
    float a0 = bd2j, a1 = bd2j;
#pragma unroll 8
    for (int k = 0; k < 128; ++k) {
        float wv = Wd2[k * 128 + j];
        a0 = fmaf(h1sh[g * 2][k], wv, a0);
        a1 = fmaf(h1sh[g * 2 + 1][k], wv, a1);
    }
    h2d[(size_t)ra * 128 + j]       = f2bf(fmaxf(a0, 0.f));
    h2d[(size_t)(ra + 1) * 128 + j] = f2bf(fmaxf(a1, 0.f));
}

// =====================================================================
// big decoder GEMM: [2048,128] @ [128,2500], BOTH heads per block
// (A staged once, which-loop over mu/sigma), fused epilogue
// =====================================================================
__global__ __launch_bounds__(256) void k_gemm(
    const unsigned short* __restrict__ h2d, const unsigned short* __restrict__ wdp,
    const float* __restrict__ bdmu, const float* __restrict__ bdsg,
    float* __restrict__ out)
{
    __shared__ __align__(16) unsigned short Al[64 * 128];
    int t = threadIdx.x, lane = t & 63, w = t >> 6;
    int m0 = blockIdx.x * 64;
#pragma unroll
    for (int i = 0; i < 4; ++i) {
        int g = t + i * 256;
        int row = g >> 4, bk = g & 15;
        uint4 v = *(const uint4*)&h2d[(size_t)(m0 + row) * 128 + bk * 8];
        *(uint4*)&Al[row * 128 + ((bk ^ (row & 7)) << 3)] = v;
    }
    __syncthreads();
    int nt = blockIdx.y * 4 + w;
    if (nt < 157) {
        int lcol = lane & 15, lq = lane >> 4;
        int col = nt * 16 + lcol;
#pragma unroll
        for (int which = 0; which < 2; ++which) {
            const unsigned short* wp = wdp + (size_t)which * (157 * 4 * 64 * 8);
            s8v bfr[4];
#pragma unroll
            for (int ks = 0; ks < 4; ++ks)
                bfr[ks] = *(const s8v*)&wp[((nt * 4 + ks) * 64 + lane) * 8];
            f4v acc[4];
            {
                f4v zf = {0.f, 0.f, 0.f, 0.f};
#pragma unroll
                for (int mt = 0; mt < 4; ++mt) acc[mt] = zf;
            }
#pragma unroll
            for (int mt = 0; mt < 4; ++mt) {
                int mrow = mt * 16 + lcol;
#pragma unroll
                for (int ks = 0; ks < 4; ++ks) {
                    int bk = ks * 4 + lq;
                    s8v a = *(const s8v*)&Al[mrow * 128 + ((bk ^ (mrow & 7)) << 3)];
                    acc[mt] = __builtin_amdgcn_mfma_f32_16x16x32_bf16(a, bfr[ks], acc[mt], 0, 0, 0);
                }
            }
            if (col < 2500) {
                const float* bp = which ? bdsg : bdmu;
                float bv = bp[col];
                size_t zoff = (size_t)which * 5120000;
#pragma unroll
                for (int mt = 0; mt < 4; ++mt)
#pragma unroll
                    for (int r = 0; r < 4; ++r) {
                        int row = m0 + mt * 16 + lq * 4 + r;
                        float vv = acc[mt][r] + bv;
                        if (which) {
                            float sp = fmaxf(vv, 0.f) + log1pf(expf(-fabsf(vv)));
                            vv = 0.1f + 0.9f * sp;
                        }
                        out[zoff + (size_t)row * 2500 + col] = vv;
                    }
            }
        }
    }
}

// =====================================================================
extern "C" void kernel_launch(void* const* d_in, const int* in_sizes, int n_in,
                              void* d_out, int out_size, void* d_ws, size_t ws_size,
                              hipStream_t stream)
{
    const float* xc   = (const float*)d_in[0];
    const float* yc   = (const float*)d_in[1];
    const float* xt   = (const float*)d_in[2];
    const float* eps  = (const float*)d_in[3];
    const float* w1   = (const float*)d_in[4];
    const float* b1   = (const float*)d_in[5];
    const float* w2   = (const float*)d_in[6];
    const float* b2   = (const float*)d_in[7];
    const float* We1  = (const float*)d_in[8];
    const float* be1  = (const float*)d_in[9];
    const float* We2  = (const float*)d_in[10];
    const float* be2  = (const float*)d_in[11];
    const float* Wh   = (const float*)d_in[12];
    const float* bh   = (const float*)d_in[13];
    const float* Wmu  = (const float*)d_in[14];
    const float* bmu  = (const float*)d_in[15];
    const float* Wsig = (const float*)d_in[16];
    const float* bsig = (const float*)d_in[17];
    const float* Wd1  = (const float*)d_in[18];
    const float* bd1  = (const float*)d_in[19];
    const float* Wd2  = (const float*)d_in[20];
    const float* bd2  = (const float*)d_in[21];
    const float* Wdmu = (const float*)d_in[22];
    const float* bdmu = (const float*)d_in[23];
    const float* Wdsg = (const float*)d_in[24];
    const float* bdsg = (const float*)d_in[25];

    float* out = (float*)d_out;
    char* wsb  = (char*)d_ws;
    unsigned short* w2p = (unsigned short*)(wsb + 0);
    unsigned short* wdp = (unsigned short*)(wsb + 18432);
    float* part = (float*)(wsb + 1304576);
    float* r_i  = (float*)(wsb + 1959936);
    float* zbuf = (float*)(wsb + 2484224);
    unsigned short* h2d = (unsigned short*)(wsb + 2488320);
    unsigned short* w1p = (unsigned short*)(wsb + 3012608);

    hipLaunchKernelGGL(k_pack, dim3(157, 3), dim3(256), 0, stream,
                       w1, b1, w2, w2p, w1p, Wdmu, Wdsg, wdp);
    hipLaunchKernelGGL(k_conv, dim3(BN * NSTRIP), dim3(256), 0, stream,
                       xc, yc, w1p, w2p, b2, part);
    hipLaunchKernelGGL(k_enc, dim3(BN), dim3(128), 0, stream,
                       part, xc, We1, be1, We2, be2, r_i);
    hipLaunchKernelGGL(k_ms, dim3(BATCH), dim3(256), 0, stream,
                       r_i, Wh, bh, Wmu, bmu, Wsig, bsig, eps, out, zbuf);
    hipLaunchKernelGGL(k_dec1, dim3(512), dim3(256), 0, stream,
                       xt, zbuf, Wd1, bd1, Wd2, bd2, h2d);
    hipLaunchKernelGGL(k_gemm, dim3(32, 40), dim3(256), 0, stream,
                       h2d, wdp, bdmu, bdsg, out);
}